// Round 3
// baseline (545.025 us; speedup 1.0000x reference)
//
#include <hip/hip_runtime.h>

// Dims
#define NB 8
#define NC 32
#define NCP 33
#define NW 256
#define NH 128
#define NX 720
#define NY 361

typedef __attribute__((ext_vector_type(8)))  short short8;
typedef __attribute__((ext_vector_type(16))) float f32x16;

// fp32 -> bf16 round-to-nearest-even
static __device__ __forceinline__ unsigned short f2bf(float f) {
    union { float f; unsigned int u; } v; v.f = f;
    unsigned int r = (v.u + 0x7FFFu + ((v.u >> 16) & 1u)) >> 16;
    return (unsigned short)r;
}

// K1: w0t[b][x][w] bf16
__global__ __launch_bounds__(256) void rbf_w0_kernel(
    const float* __restrict__ lon_in, const float* __restrict__ lon_out,
    const float* __restrict__ ls, unsigned short* __restrict__ w0t)
{
    int idx = blockIdx.x * 256 + threadIdx.x;   // exact grid: 8*720*256
    int w = idx & (NW - 1);
    int r = idx >> 8;
    int x = r % NX;
    int b = r / NX;
    float l = ls[0];
    float inv = -0.5f / (l * l);
    float d = lon_in[b * NW + w] - lon_out[b * NX + x];
    w0t[idx] = f2bf(__expf(inv * d * d));
}

// K2: w1t[b][y][h] bf16
__global__ __launch_bounds__(256) void rbf_w1_kernel(
    const float* __restrict__ lat_in, const float* __restrict__ lat_out,
    const float* __restrict__ ls, unsigned short* __restrict__ w1t)
{
    int idx = blockIdx.x * 256 + threadIdx.x;   // exact grid: 8*361*128
    int h = idx & (NH - 1);
    int r = idx >> 7;
    int y = r % NY;
    int b = r / NY;
    float l = ls[0];
    float inv = -0.5f / (l * l);
    float d = lat_in[b * NH + h] - lat_out[b * NY + y];
    w1t[idx] = f2bf(__expf(inv * d * d));
}

// K3: wtT[b][c(33)][h(128)][w(256)] bf16 — transposed, NaN-fixed, c=0 = density mask.
__global__ __launch_bounds__(256) void prep_wtT_kernel(
    const float* __restrict__ wt, unsigned short* __restrict__ wtT)
{
    __shared__ float tile[64 * 129];
    const int bc = blockIdx.z;
    const int b = bc / NCP;
    const int c = bc - b * NCP;
    const int w0 = blockIdx.x * 64;
    const bool dens = (c == 0);
    const float* src = wt + ((size_t)b * NC + (dens ? 0 : (c - 1))) * (NW * NH);

    const int r4 = threadIdx.x >> 5;   // 0..7
    const int c4 = threadIdx.x & 31;   // float4 col
    #pragma unroll
    for (int p = 0; p < 8; ++p) {
        int r = r4 + p * 8;
        float4 v = *(const float4*)&src[(size_t)(w0 + r) * NH + c4 * 4];
        float o0 = (v.x != v.x) ? 0.f : (dens ? 1.f : v.x);
        float o1 = (v.y != v.y) ? 0.f : (dens ? 1.f : v.y);
        float o2 = (v.z != v.z) ? 0.f : (dens ? 1.f : v.z);
        float o3 = (v.w != v.w) ? 0.f : (dens ? 1.f : v.w);
        float* tp = &tile[r * 129 + c4 * 4];
        tp[0] = o0; tp[1] = o1; tp[2] = o2; tp[3] = o3;
    }
    __syncthreads();

    unsigned short* dst = wtT + (size_t)bc * (NH * NW);
    #pragma unroll
    for (int p = 0; p < 4; ++p) {
        int ch = threadIdx.x + p * 256;
        int wc = ch & 7;          // which 8-w chunk in this 64-w tile
        int h  = ch >> 3;         // 0..127
        unsigned int u[4];
        #pragma unroll
        for (int j = 0; j < 4; ++j) {
            unsigned int lo = f2bf(tile[(wc * 8 + 2 * j    ) * 129 + h]);
            unsigned int hi = f2bf(tile[(wc * 8 + 2 * j + 1) * 129 + h]);
            u[j] = lo | (hi << 16);
        }
        uint4 q = make_uint4(u[0], u[1], u[2], u[3]);
        *(uint4*)&dst[(size_t)h * NW + w0 + wc * 8] = q;
    }
}

// Stage 1: T[bc][x][h] = sum_w w0t[b][x][w] * wtT[bc][h][w]
// Per (b,c): M=720 (6 tiles of 128), N=128 (full), K=256 (BK=64 x 4).
// 4 waves, wave tile 64x64 = 2x2 fragments of 32x32x16. 36.9 KB LDS ->
// 4 blocks/CU (16 waves/CU). 16-MFMA bursts between barriers.
__global__ __launch_bounds__(256, 4) void stage1_gemm(
    const unsigned short* __restrict__ w0t,
    const unsigned short* __restrict__ wtT,
    unsigned short* __restrict__ tbuf)
{
    __shared__ __align__(16) unsigned short As[128 * 72];
    __shared__ __align__(16) unsigned short Bs[128 * 72];

    const int x0 = blockIdx.x * 128;
    const int bc = blockIdx.y;
    const int b  = bc / NCP;

    const int tid  = threadIdx.x;
    const int lane = tid & 63;
    const int wv   = tid >> 6;
    const int l31  = lane & 31;
    const int lk   = lane >> 5;
    const int mw   = (wv & 1) * 64;
    const int nw   = (wv >> 1) * 64;

    const unsigned short* Ap = w0t + (size_t)b * NX * NW;
    const unsigned short* Bp = wtT + (size_t)bc * NH * NW;

    f32x16 acc[2][2];
    #pragma unroll
    for (int i = 0; i < 2; ++i)
        #pragma unroll
        for (int j = 0; j < 2; ++j)
            #pragma unroll
            for (int e = 0; e < 16; ++e) acc[i][j][e] = 0.f;

    for (int k0 = 0; k0 < NW; k0 += 64) {
        // Stage A (128x64) + B (128x64): flat-coalesced, 4 uint4 each per thread.
        #pragma unroll
        for (int p = 0; p < 4; ++p) {
            int f  = (tid + p * 256) * 8;   // short index in 128x64 tile
            int r  = f >> 6;                // row 0..127
            int cc = f & 63;                // col (16B-aligned chunks)
            int xr = x0 + r; if (xr > NX - 1) xr = NX - 1;
            *(uint4*)&As[r * 72 + cc] = *(const uint4*)&Ap[(size_t)xr * NW + k0 + cc];
            *(uint4*)&Bs[r * 72 + cc] = *(const uint4*)&Bp[(size_t)r  * NW + k0 + cc];
        }
        __syncthreads();
        #pragma unroll
        for (int ks = 0; ks < 4; ++ks) {
            const int ko = ks * 16 + lk * 8;
            short8 a0 = *(const short8*)&As[(mw      + l31) * 72 + ko];
            short8 a1 = *(const short8*)&As[(mw + 32 + l31) * 72 + ko];
            short8 b0 = *(const short8*)&Bs[(nw      + l31) * 72 + ko];
            short8 b1 = *(const short8*)&Bs[(nw + 32 + l31) * 72 + ko];
            acc[0][0] = __builtin_amdgcn_mfma_f32_32x32x16_bf16(a0, b0, acc[0][0], 0, 0, 0);
            acc[0][1] = __builtin_amdgcn_mfma_f32_32x32x16_bf16(a0, b1, acc[0][1], 0, 0, 0);
            acc[1][0] = __builtin_amdgcn_mfma_f32_32x32x16_bf16(a1, b0, acc[1][0], 0, 0, 0);
            acc[1][1] = __builtin_amdgcn_mfma_f32_32x32x16_bf16(a1, b1, acc[1][1], 0, 0, 0);
        }
        __syncthreads();
    }

    // Write T: 32x32 C layout row=(r&3)+8*(r>>2)+4*lk, col=l31.
    unsigned short* Tp = tbuf + (size_t)bc * NX * NH;
    #pragma unroll
    for (int mi = 0; mi < 2; ++mi)
        #pragma unroll
        for (int ni = 0; ni < 2; ++ni)
            #pragma unroll
            for (int r = 0; r < 16; ++r) {
                int rowf = (r & 3) + 8 * (r >> 2) + 4 * lk;
                int x = x0 + mw + mi * 32 + rowf;
                if (x < NX)
                    Tp[(size_t)x * NH + nw + ni * 32 + l31] = f2bf(acc[mi][ni][r]);
            }
}

// Stage 2: out[bc][x][y] = sum_h T[bc][x][h] * w1t[b][y][h]   (+ fused division)
// Block = 128x x 128y tile, K=128 staged ONCE -> one barrier -> 32 consecutive
// MFMAs/wave -> epilogue. 69.6 KB LDS -> 2 blocks/CU. 4 waves, 64x64/wave.
template <bool DIV>
__global__ __launch_bounds__(256, 2) void stage2_gemm(
    const unsigned short* __restrict__ tbuf,
    const unsigned short* __restrict__ w1t,
    float* __restrict__ out)
{
    __shared__ __align__(16) unsigned short As[128 * 136];
    __shared__ __align__(16) unsigned short Bs[128 * 136];

    int b, c;
    if (DIV) { b = blockIdx.z >> 5; c = 1 + (blockIdx.z & 31); }
    else     { b = blockIdx.z;      c = 0; }
    const int bc = b * NCP + c;
    const int x0 = blockIdx.x * 128;
    const int y0 = blockIdx.y * 128;

    const int tid  = threadIdx.x;
    const int lane = tid & 63;
    const int wv   = tid >> 6;
    const int l31  = lane & 31;
    const int lk   = lane >> 5;
    const int mw   = (wv & 1) * 64;
    const int nw   = (wv >> 1) * 64;

    const unsigned short* Ap = tbuf + (size_t)bc * NX * NH;
    const unsigned short* Bp = w1t + (size_t)b * NY * NH;

    // Stage A (T rows) + B (w1t rows), 32 KB each: 8 uint4 per thread per matrix.
    #pragma unroll
    for (int p = 0; p < 8; ++p) {
        int f  = (tid + p * 256) * 8;   // short index in 128x128 tile
        int r  = f >> 7;                // row 0..127
        int cc = f & 127;               // col
        int xr = x0 + r; if (xr > NX - 1) xr = NX - 1;
        int yr = y0 + r; if (yr > NY - 1) yr = NY - 1;
        *(uint4*)&As[r * 136 + cc] = *(const uint4*)&Ap[(size_t)xr * NH + cc];
        *(uint4*)&Bs[r * 136 + cc] = *(const uint4*)&Bp[(size_t)yr * NH + cc];
    }
    __syncthreads();

    f32x16 acc[2][2];
    #pragma unroll
    for (int i = 0; i < 2; ++i)
        #pragma unroll
        for (int j = 0; j < 2; ++j)
            #pragma unroll
            for (int e = 0; e < 16; ++e) acc[i][j][e] = 0.f;

    #pragma unroll
    for (int ks = 0; ks < 8; ++ks) {
        const int ko = ks * 16 + lk * 8;
        short8 a0 = *(const short8*)&As[(mw      + l31) * 136 + ko];
        short8 a1 = *(const short8*)&As[(mw + 32 + l31) * 136 + ko];
        short8 b0 = *(const short8*)&Bs[(nw      + l31) * 136 + ko];
        short8 b1 = *(const short8*)&Bs[(nw + 32 + l31) * 136 + ko];
        acc[0][0] = __builtin_amdgcn_mfma_f32_32x32x16_bf16(a0, b0, acc[0][0], 0, 0, 0);
        acc[0][1] = __builtin_amdgcn_mfma_f32_32x32x16_bf16(a0, b1, acc[0][1], 0, 0, 0);
        acc[1][0] = __builtin_amdgcn_mfma_f32_32x32x16_bf16(a1, b0, acc[1][0], 0, 0, 0);
        acc[1][1] = __builtin_amdgcn_mfma_f32_32x32x16_bf16(a1, b1, acc[1][1], 0, 0, 0);
    }

    // Epilogue. Density plane (c=0) is disjoint from written planes (c>=1),
    // so restrict-qualified locals let loads batch ahead of stores.
    const size_t plane = (size_t)NX * NY;
    float* __restrict__ Cp = out + (size_t)bc * plane;
    const float* __restrict__ Dp = out + (size_t)(b * NCP) * plane;

    #pragma unroll
    for (int mi = 0; mi < 2; ++mi)
        #pragma unroll
        for (int ni = 0; ni < 2; ++ni) {
            const int y = y0 + nw + ni * 32 + l31;
            float dv[16];
            if (DIV) {
                #pragma unroll
                for (int r = 0; r < 16; ++r) {
                    int rowf = (r & 3) + 8 * (r >> 2) + 4 * lk;
                    int x = x0 + mw + mi * 32 + rowf;
                    dv[r] = (x < NX && y < NY) ? Dp[(size_t)x * NY + y] : 1.f;
                }
            }
            #pragma unroll
            for (int r = 0; r < 16; ++r) {
                int rowf = (r & 3) + 8 * (r >> 2) + 4 * lk;
                int x = x0 + mw + mi * 32 + rowf;
                if (x < NX && y < NY) {
                    float val = acc[mi][ni][r];
                    if (DIV) {
                        float d2 = fminf(fmaxf(dv[r], 1e-6f), 1e5f);
                        val /= d2;
                    }
                    Cp[(size_t)x * NY + y] = val;
                }
            }
        }
}

extern "C" void kernel_launch(void* const* d_in, const int* in_sizes, int n_in,
                              void* d_out, int out_size, void* d_ws, size_t ws_size,
                              hipStream_t stream)
{
    const float* wt      = (const float*)d_in[0];
    const float* lon_in  = (const float*)d_in[1];
    const float* lat_in  = (const float*)d_in[2];
    const float* lon_out = (const float*)d_in[3];
    const float* lat_out = (const float*)d_in[4];
    const float* ls      = (const float*)d_in[5];
    float* out = (float*)d_out;

    // Workspace (ushort): w0t | w1t | wtT | T  — ~69.7 MB (same as R0 layout)
    unsigned short* w0t  = (unsigned short*)d_ws;
    unsigned short* w1t  = w0t + (size_t)NB * NX * NW;            // 1,474,560
    unsigned short* wtT  = w1t + (size_t)NB * NY * NH;            // +369,664
    unsigned short* tbuf = wtT + (size_t)NB * NCP * NH * NW;      // +8,650,752

    rbf_w0_kernel<<<(NB * NX * NW) / 256, 256, 0, stream>>>(lon_in, lon_out, ls, w0t);
    rbf_w1_kernel<<<(NB * NY * NH) / 256, 256, 0, stream>>>(lat_in, lat_out, ls, w1t);

    dim3 g3(4, 1, NB * NCP);
    prep_wtT_kernel<<<g3, 256, 0, stream>>>(wt, wtT);

    dim3 g1(6, NB * NCP);                    // 6 x-tiles x 264 (b,c)
    stage1_gemm<<<g1, 256, 0, stream>>>(w0t, wtT, tbuf);

    dim3 g2a(6, 3, NB);                      // density plane first
    stage2_gemm<false><<<g2a, 256, 0, stream>>>(tbuf, w1t, out);

    dim3 g2b(6, 3, NB * NC);                 // data channels, fused division
    stage2_gemm<true><<<g2b, 256, 0, stream>>>(tbuf, w1t, out);
}

// Round 4
// 450.273 us; speedup vs baseline: 1.2104x; 1.2104x over previous
//
#include <hip/hip_runtime.h>

// Dims
#define NB 8
#define NC 32
#define NCP 33
#define NW 256
#define NH 128
#define NX 720
#define NY 361

typedef __attribute__((ext_vector_type(8)))  short short8;
typedef __attribute__((ext_vector_type(16))) float f32x16;

// fp32 -> bf16 round-to-nearest-even
static __device__ __forceinline__ unsigned short f2bf(float f) {
    union { float f; unsigned int u; } v; v.f = f;
    unsigned int r = (v.u + 0x7FFFu + ((v.u >> 16) & 1u)) >> 16;
    return (unsigned short)r;
}

// K1: w0t[b][x][w] bf16
__global__ __launch_bounds__(256) void rbf_w0_kernel(
    const float* __restrict__ lon_in, const float* __restrict__ lon_out,
    const float* __restrict__ ls, unsigned short* __restrict__ w0t)
{
    int idx = blockIdx.x * 256 + threadIdx.x;   // exact grid: 8*720*256
    int w = idx & (NW - 1);
    int r = idx >> 8;
    int x = r % NX;
    int b = r / NX;
    float l = ls[0];
    float inv = -0.5f / (l * l);
    float d = lon_in[b * NW + w] - lon_out[b * NX + x];
    w0t[idx] = f2bf(__expf(inv * d * d));
}

// K2: w1t[b][y][h] bf16
__global__ __launch_bounds__(256) void rbf_w1_kernel(
    const float* __restrict__ lat_in, const float* __restrict__ lat_out,
    const float* __restrict__ ls, unsigned short* __restrict__ w1t)
{
    int idx = blockIdx.x * 256 + threadIdx.x;   // exact grid: 8*361*128
    int h = idx & (NH - 1);
    int r = idx >> 7;
    int y = r % NY;
    int b = r / NY;
    float l = ls[0];
    float inv = -0.5f / (l * l);
    float d = lat_in[b * NH + h] - lat_out[b * NY + y];
    w1t[idx] = f2bf(__expf(inv * d * d));
}

// K3: wtT[b][c(33)][h(128)][w(256)] bf16 — transposed, NaN-fixed, c=0 = density mask.
__global__ __launch_bounds__(256) void prep_wtT_kernel(
    const float* __restrict__ wt, unsigned short* __restrict__ wtT)
{
    __shared__ float tile[64 * 129];
    const int bc = blockIdx.z;
    const int b = bc / NCP;
    const int c = bc - b * NCP;
    const int w0 = blockIdx.x * 64;
    const bool dens = (c == 0);
    const float* src = wt + ((size_t)b * NC + (dens ? 0 : (c - 1))) * (NW * NH);

    const int r4 = threadIdx.x >> 5;   // 0..7
    const int c4 = threadIdx.x & 31;   // float4 col
    #pragma unroll
    for (int p = 0; p < 8; ++p) {
        int r = r4 + p * 8;
        float4 v = *(const float4*)&src[(size_t)(w0 + r) * NH + c4 * 4];
        float o0 = (v.x != v.x) ? 0.f : (dens ? 1.f : v.x);
        float o1 = (v.y != v.y) ? 0.f : (dens ? 1.f : v.y);
        float o2 = (v.z != v.z) ? 0.f : (dens ? 1.f : v.z);
        float o3 = (v.w != v.w) ? 0.f : (dens ? 1.f : v.w);
        float* tp = &tile[r * 129 + c4 * 4];
        tp[0] = o0; tp[1] = o1; tp[2] = o2; tp[3] = o3;
    }
    __syncthreads();

    unsigned short* dst = wtT + (size_t)bc * (NH * NW);
    #pragma unroll
    for (int p = 0; p < 4; ++p) {
        int ch = threadIdx.x + p * 256;
        int wc = ch & 7;          // which 8-w chunk in this 64-w tile
        int h  = ch >> 3;         // 0..127
        unsigned int u[4];
        #pragma unroll
        for (int j = 0; j < 4; ++j) {
            unsigned int lo = f2bf(tile[(wc * 8 + 2 * j    ) * 129 + h]);
            unsigned int hi = f2bf(tile[(wc * 8 + 2 * j + 1) * 129 + h]);
            u[j] = lo | (hi << 16);
        }
        uint4 q = make_uint4(u[0], u[1], u[2], u[3]);
        *(uint4*)&dst[(size_t)h * NW + w0 + wc * 8] = q;
    }
}

// Stage 1: T[bc][x][h] = sum_w w0t[b][x][w] * wtT[bc][h][w]
// 128x128 tile, BK=64, 4 waves of 2x2 32x32x16 fragments. T rows are 256B
// aligned -> full-line writes, no RMW. Unchanged from prior round (passing).
__global__ __launch_bounds__(256, 4) void stage1_gemm(
    const unsigned short* __restrict__ w0t,
    const unsigned short* __restrict__ wtT,
    unsigned short* __restrict__ tbuf)
{
    __shared__ __align__(16) unsigned short As[128 * 72];
    __shared__ __align__(16) unsigned short Bs[128 * 72];

    const int x0 = blockIdx.x * 128;
    const int bc = blockIdx.y;
    const int b  = bc / NCP;

    const int tid  = threadIdx.x;
    const int lane = tid & 63;
    const int wv   = tid >> 6;
    const int l31  = lane & 31;
    const int lk   = lane >> 5;
    const int mw   = (wv & 1) * 64;
    const int nw   = (wv >> 1) * 64;

    const unsigned short* Ap = w0t + (size_t)b * NX * NW;
    const unsigned short* Bp = wtT + (size_t)bc * NH * NW;

    f32x16 acc[2][2];
    #pragma unroll
    for (int i = 0; i < 2; ++i)
        #pragma unroll
        for (int j = 0; j < 2; ++j)
            #pragma unroll
            for (int e = 0; e < 16; ++e) acc[i][j][e] = 0.f;

    for (int k0 = 0; k0 < NW; k0 += 64) {
        #pragma unroll
        for (int p = 0; p < 4; ++p) {
            int f  = (tid + p * 256) * 8;   // short index in 128x64 tile
            int r  = f >> 6;                // row 0..127
            int cc = f & 63;                // col
            int xr = x0 + r; if (xr > NX - 1) xr = NX - 1;
            *(uint4*)&As[r * 72 + cc] = *(const uint4*)&Ap[(size_t)xr * NW + k0 + cc];
            *(uint4*)&Bs[r * 72 + cc] = *(const uint4*)&Bp[(size_t)r  * NW + k0 + cc];
        }
        __syncthreads();
        #pragma unroll
        for (int ks = 0; ks < 4; ++ks) {
            const int ko = ks * 16 + lk * 8;
            short8 a0 = *(const short8*)&As[(mw      + l31) * 72 + ko];
            short8 a1 = *(const short8*)&As[(mw + 32 + l31) * 72 + ko];
            short8 b0 = *(const short8*)&Bs[(nw      + l31) * 72 + ko];
            short8 b1 = *(const short8*)&Bs[(nw + 32 + l31) * 72 + ko];
            acc[0][0] = __builtin_amdgcn_mfma_f32_32x32x16_bf16(a0, b0, acc[0][0], 0, 0, 0);
            acc[0][1] = __builtin_amdgcn_mfma_f32_32x32x16_bf16(a0, b1, acc[0][1], 0, 0, 0);
            acc[1][0] = __builtin_amdgcn_mfma_f32_32x32x16_bf16(a1, b0, acc[1][0], 0, 0, 0);
            acc[1][1] = __builtin_amdgcn_mfma_f32_32x32x16_bf16(a1, b1, acc[1][1], 0, 0, 0);
        }
        __syncthreads();
    }

    unsigned short* Tp = tbuf + (size_t)bc * NX * NH;
    #pragma unroll
    for (int mi = 0; mi < 2; ++mi)
        #pragma unroll
        for (int ni = 0; ni < 2; ++ni)
            #pragma unroll
            for (int r = 0; r < 16; ++r) {
                int rowf = (r & 3) + 8 * (r >> 2) + 4 * lk;
                int x = x0 + mw + mi * 32 + rowf;
                if (x < NX)
                    Tp[(size_t)x * NH + nw + ni * 32 + l31] = f2bf(acc[mi][ni][r]);
            }
}

// Stage 2 streamer: block = 64 x-rows x FULL y(361) of one (b,c).
// MFMA results land in fp32 LDS tile Os[64][361] (packed = output region
// layout), then a 1D float4 stream writes the contiguous, 64B-aligned
// 64x1444B region: every store = full aligned lines, zero RMW.
// T is read exactly once (no y-tile redundancy).
// LDS: As 17.0K + Bs 34.0K + Os 90.25K = 141.3 KB -> 1 block/CU.
template <bool DIV>
__global__ __launch_bounds__(256, 1) void stage2_stream(
    const unsigned short* __restrict__ tbuf,
    const unsigned short* __restrict__ w1t,
    float* __restrict__ out)
{
    __shared__ __align__(16) unsigned short As[64 * 136];    // T x-tile [64][128]
    __shared__ __align__(16) unsigned short Bs[128 * 136];   // w1t y-chunk [128][128]
    __shared__ __align__(16) float Os[64 * 361];             // fp32 out tile

    int b, c;
    if (DIV) { b = (int)blockIdx.y >> 5; c = 1 + ((int)blockIdx.y & 31); }
    else     { b = (int)blockIdx.y;      c = 0; }
    const int bc = b * NCP + c;
    const int x0 = blockIdx.x * 64;      // 12 tiles: 0..704 (last has 16 live rows)

    const int tid  = threadIdx.x;
    const int lane = tid & 63;
    const int wv   = tid >> 6;
    const int l31  = lane & 31;
    const int lk   = lane >> 5;
    const int mw   = (wv & 1) * 32;      // x sub-tile (32)
    const int nwv  = (wv >> 1) * 64;     // y sub-tile (64 = 2 fragments)

    const unsigned short* Ap = tbuf + (size_t)bc * NX * NH;
    const unsigned short* Bp = w1t + (size_t)b * NY * NH;

    // Stage As: 64x128 shorts = 1024 uint4, 4 per thread.
    #pragma unroll
    for (int p = 0; p < 4; ++p) {
        int f  = (tid + p * 256) * 8;
        int r  = f >> 7;                 // 0..63
        int cc = f & 127;
        int xr = x0 + r; if (xr > NX - 1) xr = NX - 1;
        *(uint4*)&As[r * 136 + cc] = *(const uint4*)&Ap[(size_t)xr * NH + cc];
    }

    for (int ych = 0; ych < 384; ych += 128) {
        // Stage Bs: 128x128 shorts = 2048 uint4, 8 per thread.
        #pragma unroll
        for (int p = 0; p < 8; ++p) {
            int f  = (tid + p * 256) * 8;
            int r  = f >> 7;             // 0..127
            int cc = f & 127;
            int yr = ych + r; if (yr > NY - 1) yr = NY - 1;
            *(uint4*)&Bs[r * 136 + cc] = *(const uint4*)&Bp[(size_t)yr * NH + cc];
        }
        __syncthreads();

        f32x16 acc[2];
        #pragma unroll
        for (int i = 0; i < 2; ++i)
            #pragma unroll
            for (int e = 0; e < 16; ++e) acc[i][e] = 0.f;

        #pragma unroll
        for (int ks = 0; ks < 8; ++ks) {
            const int ko = ks * 16 + lk * 8;
            short8 a  = *(const short8*)&As[(mw        + l31) * 136 + ko];
            short8 b0 = *(const short8*)&Bs[(nwv       + l31) * 136 + ko];
            short8 b1 = *(const short8*)&Bs[(nwv + 32  + l31) * 136 + ko];
            acc[0] = __builtin_amdgcn_mfma_f32_32x32x16_bf16(a, b0, acc[0], 0, 0, 0);
            acc[1] = __builtin_amdgcn_mfma_f32_32x32x16_bf16(a, b1, acc[1], 0, 0, 0);
        }

        // Write fragments into Os (row = x_local, col = y). Mask y >= 361.
        #pragma unroll
        for (int ni = 0; ni < 2; ++ni) {
            const int y = ych + nwv + ni * 32 + l31;
            if (y < NY) {
                #pragma unroll
                for (int r = 0; r < 16; ++r) {
                    int xl = mw + (r & 3) + 8 * (r >> 2) + 4 * lk;
                    Os[xl * NY + y] = acc[ni][r];
                }
            }
        }
        __syncthreads();   // Bs consumed + Os quadrant visible before restage/store
    }

    // 1D stream: region [rows_eff x 361] fp32 is contiguous and 16B/64B aligned.
    const int rows_eff = (NX - x0 < 64) ? (NX - x0) : 64;
    const int n4 = rows_eff * NY / 4;        // 5776 or 1444 (both %1 exact)
    const size_t plane = (size_t)NX * NY;
    float4* __restrict__ Cb = (float4*)(out + (size_t)bc * plane + (size_t)x0 * NY);
    const float4* __restrict__ Db =
        (const float4*)(out + (size_t)(b * NCP) * plane + (size_t)x0 * NY);
    const float4* Os4 = (const float4*)Os;

    const int iters = (n4 + 255) / 256;      // 23 or 6
    for (int kb = 0; kb < iters; kb += 4) {
        float4 ov[4], dv[4];
        int g[4];
        #pragma unroll
        for (int j = 0; j < 4; ++j) {
            g[j] = tid + (kb + j) * 256;
            if (g[j] < n4) {
                ov[j] = Os4[g[j]];
                if (DIV) dv[j] = Db[g[j]];
            }
        }
        #pragma unroll
        for (int j = 0; j < 4; ++j) {
            if (g[j] < n4) {
                float4 o = ov[j];
                if (DIV) {
                    float4 d = dv[j];
                    o.x /= fminf(fmaxf(d.x, 1e-6f), 1e5f);
                    o.y /= fminf(fmaxf(d.y, 1e-6f), 1e5f);
                    o.z /= fminf(fmaxf(d.z, 1e-6f), 1e5f);
                    o.w /= fminf(fmaxf(d.w, 1e-6f), 1e5f);
                }
                Cb[g[j]] = o;
            }
        }
    }
}

extern "C" void kernel_launch(void* const* d_in, const int* in_sizes, int n_in,
                              void* d_out, int out_size, void* d_ws, size_t ws_size,
                              hipStream_t stream)
{
    const float* wt      = (const float*)d_in[0];
    const float* lon_in  = (const float*)d_in[1];
    const float* lat_in  = (const float*)d_in[2];
    const float* lon_out = (const float*)d_in[3];
    const float* lat_out = (const float*)d_in[4];
    const float* ls      = (const float*)d_in[5];
    float* out = (float*)d_out;

    // Workspace (ushort): w0t | w1t | wtT | T  — ~69.7 MB
    unsigned short* w0t  = (unsigned short*)d_ws;
    unsigned short* w1t  = w0t + (size_t)NB * NX * NW;            // 1,474,560
    unsigned short* wtT  = w1t + (size_t)NB * NY * NH;            // +369,664
    unsigned short* tbuf = wtT + (size_t)NB * NCP * NH * NW;      // +8,650,752

    rbf_w0_kernel<<<(NB * NX * NW) / 256, 256, 0, stream>>>(lon_in, lon_out, ls, w0t);
    rbf_w1_kernel<<<(NB * NY * NH) / 256, 256, 0, stream>>>(lat_in, lat_out, ls, w1t);

    dim3 g3(4, 1, NB * NCP);
    prep_wtT_kernel<<<g3, 256, 0, stream>>>(wt, wtT);

    dim3 g1(6, NB * NCP);                    // 6 x-tiles x 264 (b,c)
    stage1_gemm<<<g1, 256, 0, stream>>>(w0t, wtT, tbuf);

    dim3 g2a(12, NB);                        // density plane first (c=0)
    stage2_stream<false><<<g2a, 256, 0, stream>>>(tbuf, w1t, out);

    dim3 g2b(12, NB * NC);                   // data channels, fused division
    stage2_stream<true><<<g2b, 256, 0, stream>>>(tbuf, w1t, out);
}

// Round 5
// 428.604 us; speedup vs baseline: 1.2716x; 1.0506x over previous
//
#include <hip/hip_runtime.h>

// Dims
#define NB 8
#define NC 32
#define NCP 33
#define NW 256
#define NH 128
#define NX 720
#define NY 361

typedef __attribute__((ext_vector_type(8)))  short short8;
typedef __attribute__((ext_vector_type(16))) float f32x16;

// fp32 -> bf16 round-to-nearest-even
static __device__ __forceinline__ unsigned short f2bf(float f) {
    union { float f; unsigned int u; } v; v.f = f;
    unsigned int r = (v.u + 0x7FFFu + ((v.u >> 16) & 1u)) >> 16;
    return (unsigned short)r;
}

// K1: w0t[b][x][w] bf16
__global__ __launch_bounds__(256) void rbf_w0_kernel(
    const float* __restrict__ lon_in, const float* __restrict__ lon_out,
    const float* __restrict__ ls, unsigned short* __restrict__ w0t)
{
    int idx = blockIdx.x * 256 + threadIdx.x;   // exact grid: 8*720*256
    int w = idx & (NW - 1);
    int r = idx >> 8;
    int x = r % NX;
    int b = r / NX;
    float l = ls[0];
    float inv = -0.5f / (l * l);
    float d = lon_in[b * NW + w] - lon_out[b * NX + x];
    w0t[idx] = f2bf(__expf(inv * d * d));
}

// K2: w1t[b][y][h] bf16
__global__ __launch_bounds__(256) void rbf_w1_kernel(
    const float* __restrict__ lat_in, const float* __restrict__ lat_out,
    const float* __restrict__ ls, unsigned short* __restrict__ w1t)
{
    int idx = blockIdx.x * 256 + threadIdx.x;   // exact grid: 8*361*128
    int h = idx & (NH - 1);
    int r = idx >> 7;
    int y = r % NY;
    int b = r / NY;
    float l = ls[0];
    float inv = -0.5f / (l * l);
    float d = lat_in[b * NH + h] - lat_out[b * NY + y];
    w1t[idx] = f2bf(__expf(inv * d * d));
}

// K3: wtT[b][c(33)][h(128)][w(256)] bf16 — transposed, NaN-fixed, c=0 = density mask.
__global__ __launch_bounds__(256) void prep_wtT_kernel(
    const float* __restrict__ wt, unsigned short* __restrict__ wtT)
{
    __shared__ float tile[64 * 129];
    const int bc = blockIdx.z;
    const int b = bc / NCP;
    const int c = bc - b * NCP;
    const int w0 = blockIdx.x * 64;
    const bool dens = (c == 0);
    const float* src = wt + ((size_t)b * NC + (dens ? 0 : (c - 1))) * (NW * NH);

    const int r4 = threadIdx.x >> 5;   // 0..7
    const int c4 = threadIdx.x & 31;   // float4 col
    #pragma unroll
    for (int p = 0; p < 8; ++p) {
        int r = r4 + p * 8;
        float4 v = *(const float4*)&src[(size_t)(w0 + r) * NH + c4 * 4];
        float o0 = (v.x != v.x) ? 0.f : (dens ? 1.f : v.x);
        float o1 = (v.y != v.y) ? 0.f : (dens ? 1.f : v.y);
        float o2 = (v.z != v.z) ? 0.f : (dens ? 1.f : v.z);
        float o3 = (v.w != v.w) ? 0.f : (dens ? 1.f : v.w);
        float* tp = &tile[r * 129 + c4 * 4];
        tp[0] = o0; tp[1] = o1; tp[2] = o2; tp[3] = o3;
    }
    __syncthreads();

    unsigned short* dst = wtT + (size_t)bc * (NH * NW);
    #pragma unroll
    for (int p = 0; p < 4; ++p) {
        int ch = threadIdx.x + p * 256;
        int wc = ch & 7;          // which 8-w chunk in this 64-w tile
        int h  = ch >> 3;         // 0..127
        unsigned int u[4];
        #pragma unroll
        for (int j = 0; j < 4; ++j) {
            unsigned int lo = f2bf(tile[(wc * 8 + 2 * j    ) * 129 + h]);
            unsigned int hi = f2bf(tile[(wc * 8 + 2 * j + 1) * 129 + h]);
            u[j] = lo | (hi << 16);
        }
        uint4 q = make_uint4(u[0], u[1], u[2], u[3]);
        *(uint4*)&dst[(size_t)h * NW + w0 + wc * 8] = q;
    }
}

// Stage 1: T[bc][x][h] = sum_w w0t[b][x][w] * wtT[bc][h][w]
// 128x128 tile, BK=64, 4 waves of 2x2 32x32x16 fragments. Unchanged (passing).
__global__ __launch_bounds__(256, 4) void stage1_gemm(
    const unsigned short* __restrict__ w0t,
    const unsigned short* __restrict__ wtT,
    unsigned short* __restrict__ tbuf)
{
    __shared__ __align__(16) unsigned short As[128 * 72];
    __shared__ __align__(16) unsigned short Bs[128 * 72];

    const int x0 = blockIdx.x * 128;
    const int bc = blockIdx.y;
    const int b  = bc / NCP;

    const int tid  = threadIdx.x;
    const int lane = tid & 63;
    const int wv   = tid >> 6;
    const int l31  = lane & 31;
    const int lk   = lane >> 5;
    const int mw   = (wv & 1) * 64;
    const int nw   = (wv >> 1) * 64;

    const unsigned short* Ap = w0t + (size_t)b * NX * NW;
    const unsigned short* Bp = wtT + (size_t)bc * NH * NW;

    f32x16 acc[2][2];
    #pragma unroll
    for (int i = 0; i < 2; ++i)
        #pragma unroll
        for (int j = 0; j < 2; ++j)
            #pragma unroll
            for (int e = 0; e < 16; ++e) acc[i][j][e] = 0.f;

    for (int k0 = 0; k0 < NW; k0 += 64) {
        #pragma unroll
        for (int p = 0; p < 4; ++p) {
            int f  = (tid + p * 256) * 8;   // short index in 128x64 tile
            int r  = f >> 6;                // row 0..127
            int cc = f & 63;                // col
            int xr = x0 + r; if (xr > NX - 1) xr = NX - 1;
            *(uint4*)&As[r * 72 + cc] = *(const uint4*)&Ap[(size_t)xr * NW + k0 + cc];
            *(uint4*)&Bs[r * 72 + cc] = *(const uint4*)&Bp[(size_t)r  * NW + k0 + cc];
        }
        __syncthreads();
        #pragma unroll
        for (int ks = 0; ks < 4; ++ks) {
            const int ko = ks * 16 + lk * 8;
            short8 a0 = *(const short8*)&As[(mw      + l31) * 72 + ko];
            short8 a1 = *(const short8*)&As[(mw + 32 + l31) * 72 + ko];
            short8 b0 = *(const short8*)&Bs[(nw      + l31) * 72 + ko];
            short8 b1 = *(const short8*)&Bs[(nw + 32 + l31) * 72 + ko];
            acc[0][0] = __builtin_amdgcn_mfma_f32_32x32x16_bf16(a0, b0, acc[0][0], 0, 0, 0);
            acc[0][1] = __builtin_amdgcn_mfma_f32_32x32x16_bf16(a0, b1, acc[0][1], 0, 0, 0);
            acc[1][0] = __builtin_amdgcn_mfma_f32_32x32x16_bf16(a1, b0, acc[1][0], 0, 0, 0);
            acc[1][1] = __builtin_amdgcn_mfma_f32_32x32x16_bf16(a1, b1, acc[1][1], 0, 0, 0);
        }
        __syncthreads();
    }

    unsigned short* Tp = tbuf + (size_t)bc * NX * NH;
    #pragma unroll
    for (int mi = 0; mi < 2; ++mi)
        #pragma unroll
        for (int ni = 0; ni < 2; ++ni)
            #pragma unroll
            for (int r = 0; r < 16; ++r) {
                int rowf = (r & 3) + 8 * (r >> 2) + 4 * lk;
                int x = x0 + mw + mi * 32 + rowf;
                if (x < NX)
                    Tp[(size_t)x * NH + nw + ni * 32 + l31] = f2bf(acc[mi][ni][r]);
            }
}

// Stage 2 fused (single launch for ALL planes):
// Block = 32 x-rows x full y(361) of one (b,c). No input LDS: A/B fragments
// load straight from global (T and w1t are L2/L3-warm). Density is RECOMPUTED
// in-register from the c=0 plane of T (3 extra MFMAs/k-step, reusing B-frags;
// bit-identical accumulation order to the c=0 block's own result), so the
// kernel never reads `out` -> no cross-block ordering, one launch, and out
// traffic is pure full-line streaming writes via the packed Os LDS tile.
// LDS = Os only: 32*361*4 = 46.2 KB -> 3 blocks/CU (12 waves/CU).
__global__ __launch_bounds__(256, 3) void stage2_fused(
    const unsigned short* __restrict__ tbuf,
    const unsigned short* __restrict__ w1t,
    float* __restrict__ out)
{
    __shared__ __align__(16) float Os[32 * NY];   // packed = output region layout

    const int x0  = blockIdx.x * 32;     // 23 tiles: 0..704 (last has 16 live rows)
    const int bcy = blockIdx.y;          // 0..263
    const int b   = bcy / NCP;
    const int c   = bcy - b * NCP;
    const bool div = (c != 0);

    const int tid  = threadIdx.x;
    const int lane = tid & 63;
    const int wv   = tid >> 6;
    const int l31  = lane & 31;
    const int lk   = lane >> 5;

    const unsigned short* __restrict__ Tee = tbuf + (size_t)bcy * NX * NH;
    const unsigned short* __restrict__ Tde = tbuf + (size_t)(b * NCP) * NX * NH;
    const unsigned short* __restrict__ Vp  = w1t + (size_t)b * NY * NH;

    // A row for this lane (all waves read the same 32 x-rows; L2 broadcasts).
    int xA = x0 + l31; if (xA > NX - 1) xA = NX - 1;
    const size_t arow = (size_t)xA * NH;

    // This wave's 3 y-fragments: y = wv*96 + ni*32 + l31.
    int yc[3];
    #pragma unroll
    for (int ni = 0; ni < 3; ++ni) {
        int y = wv * 96 + ni * 32 + l31;
        yc[ni] = (y > NY - 1) ? (NY - 1) : y;
    }

    f32x16 aee[3], ade[3];
    #pragma unroll
    for (int ni = 0; ni < 3; ++ni)
        #pragma unroll
        for (int e = 0; e < 16; ++e) { aee[ni][e] = 0.f; ade[ni][e] = 0.f; }

    #pragma unroll
    for (int ks = 0; ks < 8; ++ks) {
        const int ko = ks * 16 + lk * 8;
        short8 a_e = *(const short8*)&Tee[arow + ko];
        short8 a_d;
        if (div) a_d = *(const short8*)&Tde[arow + ko];
        #pragma unroll
        for (int ni = 0; ni < 3; ++ni) {
            short8 bb = *(const short8*)&Vp[(size_t)yc[ni] * NH + ko];
            aee[ni] = __builtin_amdgcn_mfma_f32_32x32x16_bf16(a_e, bb, aee[ni], 0, 0, 0);
            if (div)
                ade[ni] = __builtin_amdgcn_mfma_f32_32x32x16_bf16(a_d, bb, ade[ni], 0, 0, 0);
        }
    }

    // Divide in-register, write packed Os. Fragment: col=l31 (y), row from reg.
    #pragma unroll
    for (int ni = 0; ni < 3; ++ni) {
        const int y = wv * 96 + ni * 32 + l31;
        if (y < NY) {
            #pragma unroll
            for (int r = 0; r < 16; ++r) {
                int xl = (r & 3) + 8 * (r >> 2) + 4 * lk;   // 0..31
                float val = aee[ni][r];
                if (div) {
                    float dv = fminf(fmaxf(ade[ni][r], 1e-6f), 1e5f);
                    val /= dv;
                }
                Os[xl * NY + y] = val;
            }
        }
    }
    __syncthreads();

    // Stream: contiguous [rows_eff x 361] fp32 region, full-line stores.
    const int rows_eff = (NX - x0 < 32) ? (NX - x0) : 32;
    const int n4 = rows_eff * NY / 4;    // 2888 or 1444 (both exact)
    float4* __restrict__ Cb =
        (float4*)(out + (size_t)bcy * NX * NY + (size_t)x0 * NY);
    const float4* Os4 = (const float4*)Os;
    for (int g = tid; g < n4; g += 256)
        Cb[g] = Os4[g];
}

extern "C" void kernel_launch(void* const* d_in, const int* in_sizes, int n_in,
                              void* d_out, int out_size, void* d_ws, size_t ws_size,
                              hipStream_t stream)
{
    const float* wt      = (const float*)d_in[0];
    const float* lon_in  = (const float*)d_in[1];
    const float* lat_in  = (const float*)d_in[2];
    const float* lon_out = (const float*)d_in[3];
    const float* lat_out = (const float*)d_in[4];
    const float* ls      = (const float*)d_in[5];
    float* out = (float*)d_out;

    // Workspace (ushort): w0t | w1t | wtT | T  — ~69.7 MB
    unsigned short* w0t  = (unsigned short*)d_ws;
    unsigned short* w1t  = w0t + (size_t)NB * NX * NW;            // 1,474,560
    unsigned short* wtT  = w1t + (size_t)NB * NY * NH;            // +369,664
    unsigned short* tbuf = wtT + (size_t)NB * NCP * NH * NW;      // +8,650,752

    rbf_w0_kernel<<<(NB * NX * NW) / 256, 256, 0, stream>>>(lon_in, lon_out, ls, w0t);
    rbf_w1_kernel<<<(NB * NY * NH) / 256, 256, 0, stream>>>(lat_in, lat_out, ls, w1t);

    dim3 g3(4, 1, NB * NCP);
    prep_wtT_kernel<<<g3, 256, 0, stream>>>(wt, wtT);

    dim3 g1(6, NB * NCP);                    // 6 x-tiles x 264 (b,c)
    stage1_gemm<<<g1, 256, 0, stream>>>(w0t, wtT, tbuf);

    dim3 g2(23, NB * NCP);                   // 23 x-tiles x 264 (b,c), ONE launch
    stage2_fused<<<g2, 256, 0, stream>>>(tbuf, w1t, out);
}

// Round 6
// 415.356 us; speedup vs baseline: 1.3122x; 1.0319x over previous
//
#include <hip/hip_runtime.h>

// Dims
#define NB 8
#define NC 32
#define NCP 33
#define NW 256
#define NH 128
#define NX 720
#define NY 361

typedef __attribute__((ext_vector_type(8)))  short short8;
typedef __attribute__((ext_vector_type(4)))  float f32x4;
typedef __attribute__((ext_vector_type(16))) float f32x16;

// fp32 -> bf16 round-to-nearest-even
static __device__ __forceinline__ unsigned short f2bf(float f) {
    union { float f; unsigned int u; } v; v.f = f;
    unsigned int r = (v.u + 0x7FFFu + ((v.u >> 16) & 1u)) >> 16;
    return (unsigned short)r;
}

// K1: w0t[b][x][w] bf16
__global__ __launch_bounds__(256) void rbf_w0_kernel(
    const float* __restrict__ lon_in, const float* __restrict__ lon_out,
    const float* __restrict__ ls, unsigned short* __restrict__ w0t)
{
    int idx = blockIdx.x * 256 + threadIdx.x;   // exact grid: 8*720*256
    int w = idx & (NW - 1);
    int r = idx >> 8;
    int x = r % NX;
    int b = r / NX;
    float l = ls[0];
    float inv = -0.5f / (l * l);
    float d = lon_in[b * NW + w] - lon_out[b * NX + x];
    w0t[idx] = f2bf(__expf(inv * d * d));
}

// K2: w1t[b][y][h] bf16
__global__ __launch_bounds__(256) void rbf_w1_kernel(
    const float* __restrict__ lat_in, const float* __restrict__ lat_out,
    const float* __restrict__ ls, unsigned short* __restrict__ w1t)
{
    int idx = blockIdx.x * 256 + threadIdx.x;   // exact grid: 8*361*128
    int h = idx & (NH - 1);
    int r = idx >> 7;
    int y = r % NY;
    int b = r / NY;
    float l = ls[0];
    float inv = -0.5f / (l * l);
    float d = lat_in[b * NH + h] - lat_out[b * NY + y];
    w1t[idx] = f2bf(__expf(inv * d * d));
}

// K3: wtT[b][c(33)][h(128)][w(256)] bf16 — transposed, NaN-fixed, c=0 = density mask.
__global__ __launch_bounds__(256) void prep_wtT_kernel(
    const float* __restrict__ wt, unsigned short* __restrict__ wtT)
{
    __shared__ float tile[64 * 129];
    const int bc = blockIdx.z;
    const int b = bc / NCP;
    const int c = bc - b * NCP;
    const int w0 = blockIdx.x * 64;
    const bool dens = (c == 0);
    const float* src = wt + ((size_t)b * NC + (dens ? 0 : (c - 1))) * (NW * NH);

    const int r4 = threadIdx.x >> 5;   // 0..7
    const int c4 = threadIdx.x & 31;   // float4 col
    #pragma unroll
    for (int p = 0; p < 8; ++p) {
        int r = r4 + p * 8;
        float4 v = *(const float4*)&src[(size_t)(w0 + r) * NH + c4 * 4];
        float o0 = (v.x != v.x) ? 0.f : (dens ? 1.f : v.x);
        float o1 = (v.y != v.y) ? 0.f : (dens ? 1.f : v.y);
        float o2 = (v.z != v.z) ? 0.f : (dens ? 1.f : v.z);
        float o3 = (v.w != v.w) ? 0.f : (dens ? 1.f : v.w);
        float* tp = &tile[r * 129 + c4 * 4];
        tp[0] = o0; tp[1] = o1; tp[2] = o2; tp[3] = o3;
    }
    __syncthreads();

    unsigned short* dst = wtT + (size_t)bc * (NH * NW);
    #pragma unroll
    for (int p = 0; p < 4; ++p) {
        int ch = threadIdx.x + p * 256;
        int wc = ch & 7;          // which 8-w chunk in this 64-w tile
        int h  = ch >> 3;         // 0..127
        unsigned int u[4];
        #pragma unroll
        for (int j = 0; j < 4; ++j) {
            unsigned int lo = f2bf(tile[(wc * 8 + 2 * j    ) * 129 + h]);
            unsigned int hi = f2bf(tile[(wc * 8 + 2 * j + 1) * 129 + h]);
            u[j] = lo | (hi << 16);
        }
        uint4 q = make_uint4(u[0], u[1], u[2], u[3]);
        *(uint4*)&dst[(size_t)h * NW + w0 + wc * 8] = q;
    }
}

// Stage 1: T[bc][x][h] = sum_w w0t[b][x][w] * wtT[bc][h][w]
// 128x128 tile, BK=64, 4 waves of 2x2 32x32x16 fragments. Unchanged (passing).
__global__ __launch_bounds__(256, 4) void stage1_gemm(
    const unsigned short* __restrict__ w0t,
    const unsigned short* __restrict__ wtT,
    unsigned short* __restrict__ tbuf)
{
    __shared__ __align__(16) unsigned short As[128 * 72];
    __shared__ __align__(16) unsigned short Bs[128 * 72];

    const int x0 = blockIdx.x * 128;
    const int bc = blockIdx.y;
    const int b  = bc / NCP;

    const int tid  = threadIdx.x;
    const int lane = tid & 63;
    const int wv   = tid >> 6;
    const int l31  = lane & 31;
    const int lk   = lane >> 5;
    const int mw   = (wv & 1) * 64;
    const int nw   = (wv >> 1) * 64;

    const unsigned short* Ap = w0t + (size_t)b * NX * NW;
    const unsigned short* Bp = wtT + (size_t)bc * NH * NW;

    f32x16 acc[2][2];
    #pragma unroll
    for (int i = 0; i < 2; ++i)
        #pragma unroll
        for (int j = 0; j < 2; ++j)
            #pragma unroll
            for (int e = 0; e < 16; ++e) acc[i][j][e] = 0.f;

    for (int k0 = 0; k0 < NW; k0 += 64) {
        #pragma unroll
        for (int p = 0; p < 4; ++p) {
            int f  = (tid + p * 256) * 8;   // short index in 128x64 tile
            int r  = f >> 6;                // row 0..127
            int cc = f & 63;                // col
            int xr = x0 + r; if (xr > NX - 1) xr = NX - 1;
            *(uint4*)&As[r * 72 + cc] = *(const uint4*)&Ap[(size_t)xr * NW + k0 + cc];
            *(uint4*)&Bs[r * 72 + cc] = *(const uint4*)&Bp[(size_t)r  * NW + k0 + cc];
        }
        __syncthreads();
        #pragma unroll
        for (int ks = 0; ks < 4; ++ks) {
            const int ko = ks * 16 + lk * 8;
            short8 a0 = *(const short8*)&As[(mw      + l31) * 72 + ko];
            short8 a1 = *(const short8*)&As[(mw + 32 + l31) * 72 + ko];
            short8 b0 = *(const short8*)&Bs[(nw      + l31) * 72 + ko];
            short8 b1 = *(const short8*)&Bs[(nw + 32 + l31) * 72 + ko];
            acc[0][0] = __builtin_amdgcn_mfma_f32_32x32x16_bf16(a0, b0, acc[0][0], 0, 0, 0);
            acc[0][1] = __builtin_amdgcn_mfma_f32_32x32x16_bf16(a0, b1, acc[0][1], 0, 0, 0);
            acc[1][0] = __builtin_amdgcn_mfma_f32_32x32x16_bf16(a1, b0, acc[1][0], 0, 0, 0);
            acc[1][1] = __builtin_amdgcn_mfma_f32_32x32x16_bf16(a1, b1, acc[1][1], 0, 0, 0);
        }
        __syncthreads();
    }

    unsigned short* Tp = tbuf + (size_t)bc * NX * NH;
    #pragma unroll
    for (int mi = 0; mi < 2; ++mi)
        #pragma unroll
        for (int ni = 0; ni < 2; ++ni)
            #pragma unroll
            for (int r = 0; r < 16; ++r) {
                int rowf = (r & 3) + 8 * (r >> 2) + 4 * lk;
                int x = x0 + mw + mi * 32 + rowf;
                if (x < NX)
                    Tp[(size_t)x * NH + nw + ni * 32 + l31] = f2bf(acc[mi][ni][r]);
            }
}

// Density kernel: plane c=0 of one b, 32 x-rows x full y.
// Writes BOTH out[b*NCP+0] (final output, nt-store) and densbuf[b][x][y]
// (compact fp32 workspace, L2/L3-resident, read by stage2_main's stream).
// Same MFMA/accumulation order as before -> bit-identical density values.
__global__ __launch_bounds__(256, 3) void dens_kernel(
    const unsigned short* __restrict__ tbuf,
    const unsigned short* __restrict__ w1t,
    float* __restrict__ out,
    float* __restrict__ densbuf)
{
    __shared__ __align__(16) float Os[32 * NY];

    const int x0 = blockIdx.x * 32;
    const int b  = blockIdx.y;

    const int tid  = threadIdx.x;
    const int lane = tid & 63;
    const int wv   = tid >> 6;
    const int l31  = lane & 31;
    const int lk   = lane >> 5;

    const unsigned short* __restrict__ Tp = tbuf + (size_t)(b * NCP) * NX * NH;
    const unsigned short* __restrict__ Vp = w1t + (size_t)b * NY * NH;

    int xA = x0 + l31; if (xA > NX - 1) xA = NX - 1;
    const size_t arow = (size_t)xA * NH;

    int yc[3];
    #pragma unroll
    for (int ni = 0; ni < 3; ++ni) {
        int y = wv * 96 + ni * 32 + l31;
        yc[ni] = (y > NY - 1) ? (NY - 1) : y;
    }

    f32x16 aee[3];
    #pragma unroll
    for (int ni = 0; ni < 3; ++ni)
        #pragma unroll
        for (int e = 0; e < 16; ++e) aee[ni][e] = 0.f;

    #pragma unroll
    for (int ks = 0; ks < 8; ++ks) {
        const int ko = ks * 16 + lk * 8;
        short8 a = *(const short8*)&Tp[arow + ko];
        #pragma unroll
        for (int ni = 0; ni < 3; ++ni) {
            short8 bb = *(const short8*)&Vp[(size_t)yc[ni] * NH + ko];
            aee[ni] = __builtin_amdgcn_mfma_f32_32x32x16_bf16(a, bb, aee[ni], 0, 0, 0);
        }
    }

    #pragma unroll
    for (int ni = 0; ni < 3; ++ni) {
        const int y = wv * 96 + ni * 32 + l31;
        if (y < NY) {
            #pragma unroll
            for (int r = 0; r < 16; ++r) {
                int xl = (r & 3) + 8 * (r >> 2) + 4 * lk;
                Os[xl * NY + y] = aee[ni][r];
            }
        }
    }
    __syncthreads();

    const int rows_eff = (NX - x0 < 32) ? (NX - x0) : 32;
    const int n4 = rows_eff * NY / 4;
    f32x4* __restrict__ Cb =
        (f32x4*)(out + (size_t)(b * NCP) * NX * NY + (size_t)x0 * NY);
    f32x4* __restrict__ Db =
        (f32x4*)(densbuf + (size_t)b * NX * NY + (size_t)x0 * NY);
    const f32x4* Os4 = (const f32x4*)Os;
    for (int g = tid; g < n4; g += 256) {
        f32x4 o = Os4[g];
        __builtin_nontemporal_store(o, &Cb[g]);   // final output: stream, no reuse
        Db[g] = o;                                 // densbuf: cached, re-read soon
    }
}

// Stage 2 main: c=1..32 only. Block = 32 x-rows x full y of one (b,c).
// No input LDS (T/w1t fragments straight from L2-warm global). No density
// MFMA recompute: division happens in the STREAM phase from densbuf (packed
// layout == Os layout -> perfectly coalesced float4 L2 reads, __restrict__,
// no aliasing with out). LDS = Os only (46.2 KB) -> 3 blocks/CU.
__global__ __launch_bounds__(256, 3) void stage2_main(
    const unsigned short* __restrict__ tbuf,
    const unsigned short* __restrict__ w1t,
    const float* __restrict__ densbuf,
    float* __restrict__ out)
{
    __shared__ __align__(16) float Os[32 * NY];

    const int x0  = blockIdx.x * 32;
    const int bcl = blockIdx.y;          // 0..255
    const int b   = bcl >> 5;
    const int c   = 1 + (bcl & 31);
    const int bcy = b * NCP + c;

    const int tid  = threadIdx.x;
    const int lane = tid & 63;
    const int wv   = tid >> 6;
    const int l31  = lane & 31;
    const int lk   = lane >> 5;

    const unsigned short* __restrict__ Tp = tbuf + (size_t)bcy * NX * NH;
    const unsigned short* __restrict__ Vp = w1t + (size_t)b * NY * NH;

    int xA = x0 + l31; if (xA > NX - 1) xA = NX - 1;
    const size_t arow = (size_t)xA * NH;

    int yc[3];
    #pragma unroll
    for (int ni = 0; ni < 3; ++ni) {
        int y = wv * 96 + ni * 32 + l31;
        yc[ni] = (y > NY - 1) ? (NY - 1) : y;
    }

    f32x16 aee[3];
    #pragma unroll
    for (int ni = 0; ni < 3; ++ni)
        #pragma unroll
        for (int e = 0; e < 16; ++e) aee[ni][e] = 0.f;

    #pragma unroll
    for (int ks = 0; ks < 8; ++ks) {
        const int ko = ks * 16 + lk * 8;
        short8 a = *(const short8*)&Tp[arow + ko];
        #pragma unroll
        for (int ni = 0; ni < 3; ++ni) {
            short8 bb = *(const short8*)&Vp[(size_t)yc[ni] * NH + ko];
            aee[ni] = __builtin_amdgcn_mfma_f32_32x32x16_bf16(a, bb, aee[ni], 0, 0, 0);
        }
    }

    #pragma unroll
    for (int ni = 0; ni < 3; ++ni) {
        const int y = wv * 96 + ni * 32 + l31;
        if (y < NY) {
            #pragma unroll
            for (int r = 0; r < 16; ++r) {
                int xl = (r & 3) + 8 * (r >> 2) + 4 * lk;
                Os[xl * NY + y] = aee[ni][r];
            }
        }
    }
    __syncthreads();

    // Stream with fused division: all three arrays share the packed layout.
    const int rows_eff = (NX - x0 < 32) ? (NX - x0) : 32;
    const int n4 = rows_eff * NY / 4;
    f32x4* __restrict__ Cb =
        (f32x4*)(out + (size_t)bcy * NX * NY + (size_t)x0 * NY);
    const f32x4* __restrict__ Db =
        (const f32x4*)(densbuf + (size_t)b * NX * NY + (size_t)x0 * NY);
    const f32x4* Os4 = (const f32x4*)Os;

    for (int g = tid; g < n4; g += 256) {
        f32x4 o = Os4[g];
        f32x4 d = Db[g];
        o.x /= fminf(fmaxf(d.x, 1e-6f), 1e5f);
        o.y /= fminf(fmaxf(d.y, 1e-6f), 1e5f);
        o.z /= fminf(fmaxf(d.z, 1e-6f), 1e5f);
        o.w /= fminf(fmaxf(d.w, 1e-6f), 1e5f);
        __builtin_nontemporal_store(o, &Cb[g]);
    }
}

extern "C" void kernel_launch(void* const* d_in, const int* in_sizes, int n_in,
                              void* d_out, int out_size, void* d_ws, size_t ws_size,
                              hipStream_t stream)
{
    const float* wt      = (const float*)d_in[0];
    const float* lon_in  = (const float*)d_in[1];
    const float* lat_in  = (const float*)d_in[2];
    const float* lon_out = (const float*)d_in[3];
    const float* lat_out = (const float*)d_in[4];
    const float* ls      = (const float*)d_in[5];
    float* out = (float*)d_out;

    // Workspace (ushort): w0t | w1t | wtT | T  — ~69.7 MB.
    // densbuf (8.3 MB fp32) OVERLAYS wtT: wtT is dead after stage1, and
    // dens_kernel/stage2_main run strictly after it (stream-ordered).
    unsigned short* w0t  = (unsigned short*)d_ws;
    unsigned short* w1t  = w0t + (size_t)NB * NX * NW;            // 1,474,560
    unsigned short* wtT  = w1t + (size_t)NB * NY * NH;            // +369,664
    unsigned short* tbuf = wtT + (size_t)NB * NCP * NH * NW;      // +8,650,752
    float* densbuf = (float*)wtT;   // 16B-aligned (offset 3,688,448 B)

    rbf_w0_kernel<<<(NB * NX * NW) / 256, 256, 0, stream>>>(lon_in, lon_out, ls, w0t);
    rbf_w1_kernel<<<(NB * NY * NH) / 256, 256, 0, stream>>>(lat_in, lat_out, ls, w1t);

    dim3 g3(4, 1, NB * NCP);
    prep_wtT_kernel<<<g3, 256, 0, stream>>>(wt, wtT);

    dim3 g1(6, NB * NCP);                    // 6 x-tiles x 264 (b,c)
    stage1_gemm<<<g1, 256, 0, stream>>>(w0t, wtT, tbuf);

    dim3 gd(23, NB);                         // density: 23 x-tiles x 8 b
    dens_kernel<<<gd, 256, 0, stream>>>(tbuf, w1t, out, densbuf);

    dim3 g2(23, NB * NC);                    // 23 x-tiles x 256 (b,c>0)
    stage2_main<<<g2, 256, 0, stream>>>(tbuf, w1t, densbuf, out);
}

// Round 7
// 390.628 us; speedup vs baseline: 1.3953x; 1.0633x over previous
//
#include <hip/hip_runtime.h>

// Dims
#define NB 8
#define NC 32
#define NCP 33
#define NW 256
#define NH 128
#define NX 720
#define NY 361

typedef __attribute__((ext_vector_type(8)))  short short8;
typedef __attribute__((ext_vector_type(4)))  float f32x4;
typedef __attribute__((ext_vector_type(16))) float f32x16;

// fp32 -> bf16 round-to-nearest-even
static __device__ __forceinline__ unsigned short f2bf(float f) {
    union { float f; unsigned int u; } v; v.f = f;
    unsigned int r = (v.u + 0x7FFFu + ((v.u >> 16) & 1u)) >> 16;
    return (unsigned short)r;
}

// K1: w0t[b][x][w] bf16
__global__ __launch_bounds__(256) void rbf_w0_kernel(
    const float* __restrict__ lon_in, const float* __restrict__ lon_out,
    const float* __restrict__ ls, unsigned short* __restrict__ w0t)
{
    int idx = blockIdx.x * 256 + threadIdx.x;   // exact grid: 8*720*256
    int w = idx & (NW - 1);
    int r = idx >> 8;
    int x = r % NX;
    int b = r / NX;
    float l = ls[0];
    float inv = -0.5f / (l * l);
    float d = lon_in[b * NW + w] - lon_out[b * NX + x];
    w0t[idx] = f2bf(__expf(inv * d * d));
}

// K2: w1t[b][y][h] bf16
__global__ __launch_bounds__(256) void rbf_w1_kernel(
    const float* __restrict__ lat_in, const float* __restrict__ lat_out,
    const float* __restrict__ ls, unsigned short* __restrict__ w1t)
{
    int idx = blockIdx.x * 256 + threadIdx.x;   // exact grid: 8*361*128
    int h = idx & (NH - 1);
    int r = idx >> 7;
    int y = r % NY;
    int b = r / NY;
    float l = ls[0];
    float inv = -0.5f / (l * l);
    float d = lat_in[b * NH + h] - lat_out[b * NY + y];
    w1t[idx] = f2bf(__expf(inv * d * d));
}

// K3: wtT[b][c(33)][h(128)][w(256)] bf16 — transposed, NaN-fixed, c=0 = density mask.
__global__ __launch_bounds__(256) void prep_wtT_kernel(
    const float* __restrict__ wt, unsigned short* __restrict__ wtT)
{
    __shared__ float tile[64 * 129];
    const int bc = blockIdx.z;
    const int b = bc / NCP;
    const int c = bc - b * NCP;
    const int w0 = blockIdx.x * 64;
    const bool dens = (c == 0);
    const float* src = wt + ((size_t)b * NC + (dens ? 0 : (c - 1))) * (NW * NH);

    const int r4 = threadIdx.x >> 5;   // 0..7
    const int c4 = threadIdx.x & 31;   // float4 col
    #pragma unroll
    for (int p = 0; p < 8; ++p) {
        int r = r4 + p * 8;
        float4 v = *(const float4*)&src[(size_t)(w0 + r) * NH + c4 * 4];
        float o0 = (v.x != v.x) ? 0.f : (dens ? 1.f : v.x);
        float o1 = (v.y != v.y) ? 0.f : (dens ? 1.f : v.y);
        float o2 = (v.z != v.z) ? 0.f : (dens ? 1.f : v.z);
        float o3 = (v.w != v.w) ? 0.f : (dens ? 1.f : v.w);
        float* tp = &tile[r * 129 + c4 * 4];
        tp[0] = o0; tp[1] = o1; tp[2] = o2; tp[3] = o3;
    }
    __syncthreads();

    unsigned short* dst = wtT + (size_t)bc * (NH * NW);
    #pragma unroll
    for (int p = 0; p < 4; ++p) {
        int ch = threadIdx.x + p * 256;
        int wc = ch & 7;          // which 8-w chunk in this 64-w tile
        int h  = ch >> 3;         // 0..127
        unsigned int u[4];
        #pragma unroll
        for (int j = 0; j < 4; ++j) {
            unsigned int lo = f2bf(tile[(wc * 8 + 2 * j    ) * 129 + h]);
            unsigned int hi = f2bf(tile[(wc * 8 + 2 * j + 1) * 129 + h]);
            u[j] = lo | (hi << 16);
        }
        uint4 q = make_uint4(u[0], u[1], u[2], u[3]);
        *(uint4*)&dst[(size_t)h * NW + w0 + wc * 8] = q;
    }
}

// Stage 1: T[bc][x][h] = sum_w w0t[b][x][w] * wtT[bc][h][w]
// 128x128 tile, BK=64, 4 waves of 2x2 32x32x16 fragments. Unchanged (passing).
__global__ __launch_bounds__(256, 4) void stage1_gemm(
    const unsigned short* __restrict__ w0t,
    const unsigned short* __restrict__ wtT,
    unsigned short* __restrict__ tbuf)
{
    __shared__ __align__(16) unsigned short As[128 * 72];
    __shared__ __align__(16) unsigned short Bs[128 * 72];

    const int x0 = blockIdx.x * 128;
    const int bc = blockIdx.y;
    const int b  = bc / NCP;

    const int tid  = threadIdx.x;
    const int lane = tid & 63;
    const int wv   = tid >> 6;
    const int l31  = lane & 31;
    const int lk   = lane >> 5;
    const int mw   = (wv & 1) * 64;
    const int nw   = (wv >> 1) * 64;

    const unsigned short* Ap = w0t + (size_t)b * NX * NW;
    const unsigned short* Bp = wtT + (size_t)bc * NH * NW;

    f32x16 acc[2][2];
    #pragma unroll
    for (int i = 0; i < 2; ++i)
        #pragma unroll
        for (int j = 0; j < 2; ++j)
            #pragma unroll
            for (int e = 0; e < 16; ++e) acc[i][j][e] = 0.f;

    for (int k0 = 0; k0 < NW; k0 += 64) {
        #pragma unroll
        for (int p = 0; p < 4; ++p) {
            int f  = (tid + p * 256) * 8;   // short index in 128x64 tile
            int r  = f >> 6;                // row 0..127
            int cc = f & 63;                // col
            int xr = x0 + r; if (xr > NX - 1) xr = NX - 1;
            *(uint4*)&As[r * 72 + cc] = *(const uint4*)&Ap[(size_t)xr * NW + k0 + cc];
            *(uint4*)&Bs[r * 72 + cc] = *(const uint4*)&Bp[(size_t)r  * NW + k0 + cc];
        }
        __syncthreads();
        #pragma unroll
        for (int ks = 0; ks < 4; ++ks) {
            const int ko = ks * 16 + lk * 8;
            short8 a0 = *(const short8*)&As[(mw      + l31) * 72 + ko];
            short8 a1 = *(const short8*)&As[(mw + 32 + l31) * 72 + ko];
            short8 b0 = *(const short8*)&Bs[(nw      + l31) * 72 + ko];
            short8 b1 = *(const short8*)&Bs[(nw + 32 + l31) * 72 + ko];
            acc[0][0] = __builtin_amdgcn_mfma_f32_32x32x16_bf16(a0, b0, acc[0][0], 0, 0, 0);
            acc[0][1] = __builtin_amdgcn_mfma_f32_32x32x16_bf16(a0, b1, acc[0][1], 0, 0, 0);
            acc[1][0] = __builtin_amdgcn_mfma_f32_32x32x16_bf16(a1, b0, acc[1][0], 0, 0, 0);
            acc[1][1] = __builtin_amdgcn_mfma_f32_32x32x16_bf16(a1, b1, acc[1][1], 0, 0, 0);
        }
        __syncthreads();
    }

    unsigned short* Tp = tbuf + (size_t)bc * NX * NH;
    #pragma unroll
    for (int mi = 0; mi < 2; ++mi)
        #pragma unroll
        for (int ni = 0; ni < 2; ++ni)
            #pragma unroll
            for (int r = 0; r < 16; ++r) {
                int rowf = (r & 3) + 8 * (r >> 2) + 4 * lk;
                int x = x0 + mw + mi * 32 + rowf;
                if (x < NX)
                    Tp[(size_t)x * NH + nw + ni * 32 + l31] = f2bf(acc[mi][ni][r]);
            }
}

// Density kernel: plane c=0 of one b, 32 x-rows x full y.
// Writes BOTH out[b*NCP+0] (final output, nt-store) and densbuf[b][x][y].
// Unchanged from R6 (passing, bit-identical density values).
__global__ __launch_bounds__(256, 3) void dens_kernel(
    const unsigned short* __restrict__ tbuf,
    const unsigned short* __restrict__ w1t,
    float* __restrict__ out,
    float* __restrict__ densbuf)
{
    __shared__ __align__(16) float Os[32 * NY];

    const int x0 = blockIdx.x * 32;
    const int b  = blockIdx.y;

    const int tid  = threadIdx.x;
    const int lane = tid & 63;
    const int wv   = tid >> 6;
    const int l31  = lane & 31;
    const int lk   = lane >> 5;

    const unsigned short* __restrict__ Tp = tbuf + (size_t)(b * NCP) * NX * NH;
    const unsigned short* __restrict__ Vp = w1t + (size_t)b * NY * NH;

    int xA = x0 + l31; if (xA > NX - 1) xA = NX - 1;
    const size_t arow = (size_t)xA * NH;

    int yc[3];
    #pragma unroll
    for (int ni = 0; ni < 3; ++ni) {
        int y = wv * 96 + ni * 32 + l31;
        yc[ni] = (y > NY - 1) ? (NY - 1) : y;
    }

    f32x16 aee[3];
    #pragma unroll
    for (int ni = 0; ni < 3; ++ni)
        #pragma unroll
        for (int e = 0; e < 16; ++e) aee[ni][e] = 0.f;

    #pragma unroll
    for (int ks = 0; ks < 8; ++ks) {
        const int ko = ks * 16 + lk * 8;
        short8 a = *(const short8*)&Tp[arow + ko];
        #pragma unroll
        for (int ni = 0; ni < 3; ++ni) {
            short8 bb = *(const short8*)&Vp[(size_t)yc[ni] * NH + ko];
            aee[ni] = __builtin_amdgcn_mfma_f32_32x32x16_bf16(a, bb, aee[ni], 0, 0, 0);
        }
    }

    #pragma unroll
    for (int ni = 0; ni < 3; ++ni) {
        const int y = wv * 96 + ni * 32 + l31;
        if (y < NY) {
            #pragma unroll
            for (int r = 0; r < 16; ++r) {
                int xl = (r & 3) + 8 * (r >> 2) + 4 * lk;
                Os[xl * NY + y] = aee[ni][r];
            }
        }
    }
    __syncthreads();

    const int rows_eff = (NX - x0 < 32) ? (NX - x0) : 32;
    const int n4 = rows_eff * NY / 4;
    f32x4* __restrict__ Cb =
        (f32x4*)(out + (size_t)(b * NCP) * NX * NY + (size_t)x0 * NY);
    f32x4* __restrict__ Db =
        (f32x4*)(densbuf + (size_t)b * NX * NY + (size_t)x0 * NY);
    const f32x4* Os4 = (const f32x4*)Os;
    for (int g = tid; g < n4; g += 256) {
        f32x4 o = Os4[g];
        __builtin_nontemporal_store(o, &Cb[g]);   // final output: stream, no reuse
        Db[g] = o;                                 // densbuf: cached, re-read soon
    }
}

// Stage 2 main, CPB=4 channels per block.
// The 24 w1t B-fragments (96 VGPRs) are loaded ONCE and held in registers
// across 4 channels — they were previously re-loaded (32-line scatter each)
// by every channel-block. Per-channel scatter-loads drop 32 -> 14.
// Per channel: 8 A-loads, 24 MFMA, Os fragment write, fused-divide stream
// (densbuf packed layout == Os layout -> coalesced float4 L2 reads).
// LDS = Os only (46.2 KB); VGPR ~190 -> 2 blocks/CU (8 waves).
__global__ __launch_bounds__(256, 2) void stage2_main(
    const unsigned short* __restrict__ tbuf,
    const unsigned short* __restrict__ w1t,
    const float* __restrict__ densbuf,
    float* __restrict__ out)
{
    __shared__ __align__(16) float Os[32 * NY];

    const int x0 = blockIdx.x * 32;
    const int bg = blockIdx.y;           // 0..63
    const int b  = bg >> 3;
    const int cg = bg & 7;               // channels 1+cg*4 .. 1+cg*4+3

    const int tid  = threadIdx.x;
    const int lane = tid & 63;
    const int wv   = tid >> 6;
    const int l31  = lane & 31;
    const int lk   = lane >> 5;

    const unsigned short* __restrict__ Vp = w1t + (size_t)b * NY * NH;

    int xA = x0 + l31; if (xA > NX - 1) xA = NX - 1;
    const size_t arow = (size_t)xA * NH;

    int yc[3];
    #pragma unroll
    for (int ni = 0; ni < 3; ++ni) {
        int y = wv * 96 + ni * 32 + l31;
        yc[ni] = (y > NY - 1) ? (NY - 1) : y;
    }

    // Load all 24 B fragments once; held in registers for the channel loop.
    short8 bfr[8][3];
    #pragma unroll
    for (int ks = 0; ks < 8; ++ks)
        #pragma unroll
        for (int ni = 0; ni < 3; ++ni)
            bfr[ks][ni] = *(const short8*)&Vp[(size_t)yc[ni] * NH + ks * 16 + lk * 8];

    const int rows_eff = (NX - x0 < 32) ? (NX - x0) : 32;
    const int n4 = rows_eff * NY / 4;
    const f32x4* __restrict__ Db =
        (const f32x4*)(densbuf + (size_t)b * NX * NY + (size_t)x0 * NY);
    const f32x4* Os4 = (const f32x4*)Os;

    #pragma unroll
    for (int ci = 0; ci < 4; ++ci) {
        const int bcy = b * NCP + 1 + cg * 4 + ci;
        const unsigned short* __restrict__ Tp = tbuf + (size_t)bcy * NX * NH;

        f32x16 aee[3];
        #pragma unroll
        for (int ni = 0; ni < 3; ++ni)
            #pragma unroll
            for (int e = 0; e < 16; ++e) aee[ni][e] = 0.f;

        #pragma unroll
        for (int ks = 0; ks < 8; ++ks) {
            short8 a = *(const short8*)&Tp[arow + ks * 16 + lk * 8];
            aee[0] = __builtin_amdgcn_mfma_f32_32x32x16_bf16(a, bfr[ks][0], aee[0], 0, 0, 0);
            aee[1] = __builtin_amdgcn_mfma_f32_32x32x16_bf16(a, bfr[ks][1], aee[1], 0, 0, 0);
            aee[2] = __builtin_amdgcn_mfma_f32_32x32x16_bf16(a, bfr[ks][2], aee[2], 0, 0, 0);
        }

        #pragma unroll
        for (int ni = 0; ni < 3; ++ni) {
            const int y = wv * 96 + ni * 32 + l31;
            if (y < NY) {
                #pragma unroll
                for (int r = 0; r < 16; ++r) {
                    int xl = (r & 3) + 8 * (r >> 2) + 4 * lk;
                    Os[xl * NY + y] = aee[ni][r];
                }
            }
        }
        __syncthreads();

        f32x4* __restrict__ Cb =
            (f32x4*)(out + (size_t)bcy * NX * NY + (size_t)x0 * NY);
        for (int g = tid; g < n4; g += 256) {
            f32x4 o = Os4[g];
            f32x4 d = Db[g];
            o.x /= fminf(fmaxf(d.x, 1e-6f), 1e5f);
            o.y /= fminf(fmaxf(d.y, 1e-6f), 1e5f);
            o.z /= fminf(fmaxf(d.z, 1e-6f), 1e5f);
            o.w /= fminf(fmaxf(d.w, 1e-6f), 1e5f);
            __builtin_nontemporal_store(o, &Cb[g]);
        }
        __syncthreads();   // Os free before next channel overwrites it
    }
}

extern "C" void kernel_launch(void* const* d_in, const int* in_sizes, int n_in,
                              void* d_out, int out_size, void* d_ws, size_t ws_size,
                              hipStream_t stream)
{
    const float* wt      = (const float*)d_in[0];
    const float* lon_in  = (const float*)d_in[1];
    const float* lat_in  = (const float*)d_in[2];
    const float* lon_out = (const float*)d_in[3];
    const float* lat_out = (const float*)d_in[4];
    const float* ls      = (const float*)d_in[5];
    float* out = (float*)d_out;

    // Workspace (ushort): w0t | w1t | wtT | T  — ~69.7 MB.
    // densbuf (8.3 MB fp32) OVERLAYS wtT (dead after stage1, stream-ordered).
    unsigned short* w0t  = (unsigned short*)d_ws;
    unsigned short* w1t  = w0t + (size_t)NB * NX * NW;            // 1,474,560
    unsigned short* wtT  = w1t + (size_t)NB * NY * NH;            // +369,664
    unsigned short* tbuf = wtT + (size_t)NB * NCP * NH * NW;      // +8,650,752
    float* densbuf = (float*)wtT;   // 16B-aligned (offset 3,688,448 B)

    rbf_w0_kernel<<<(NB * NX * NW) / 256, 256, 0, stream>>>(lon_in, lon_out, ls, w0t);
    rbf_w1_kernel<<<(NB * NY * NH) / 256, 256, 0, stream>>>(lat_in, lat_out, ls, w1t);

    dim3 g3(4, 1, NB * NCP);
    prep_wtT_kernel<<<g3, 256, 0, stream>>>(wt, wtT);

    dim3 g1(6, NB * NCP);                    // 6 x-tiles x 264 (b,c)
    stage1_gemm<<<g1, 256, 0, stream>>>(w0t, wtT, tbuf);

    dim3 gd(23, NB);                         // density: 23 x-tiles x 8 b
    dens_kernel<<<gd, 256, 0, stream>>>(tbuf, w1t, out, densbuf);

    dim3 g2(23, NB * 8);                     // 23 x-tiles x (8 b x 8 c-groups)
    stage2_main<<<g2, 256, 0, stream>>>(tbuf, w1t, densbuf, out);
}